// Round 6
// baseline (285.104 us; speedup 1.0000x reference)
//
#include <hip/hip_runtime.h>
#include <hip/hip_bf16.h>
#include <cstddef>

// OutputAttention: context = softmax_s(tanh(passage@W1 + hidden@W2)@Vw) . passage
// B=32, S=2048, D=512, U=512. All inputs fp32; outputs fp32.
// d_out = context[32*512] ++ attn[32*2048]. attn region doubles as score scratch.

#define NB 32
#define NS 2048
#define ND 512
#define NU 512

typedef __bf16 bf16_t;
typedef __bf16 bf16x8 __attribute__((ext_vector_type(8)));
typedef float floatx4 __attribute__((ext_vector_type(4)));

// ---------------------------------------------------------------------------
// K0 fused: blocks [0,128): W1 fp32->bf16 swizzle into MFMA-B fragment order,
//           one 1KB frag per wave (gather-read, coalesced 16B writes).
//           blocks [128,256): hproj[b][u] = sum_d hidden[b][d]*W2[d][u].
// B-frag layout: frag f=(kc,ng); lane L holds B[kc*32+q*8+jj][ng*16+c], jj=0..7,
// at W1p[f*512 + L*8] -> k-loop B loads are one coalesced dwordx4 per lane.
__global__ __launch_bounds__(256) void prep_kernel(
    const float* __restrict__ W1, bf16_t* __restrict__ W1p,
    const float* __restrict__ hidden, const float* __restrict__ W2,
    float* __restrict__ hproj) {
    if (blockIdx.x < 128) {
        int wave = threadIdx.x >> 6, lane = threadIdx.x & 63;
        int f = (blockIdx.x << 2) + wave;             // 0..511
        int kc = f >> 5, ng = f & 31;
        int q = lane >> 4, c = lane & 15;
        const float* src = W1 + (kc * 32 + q * 8) * 512 + ng * 16 + c;
        bf16x8 w;
#pragma unroll
        for (int jj = 0; jj < 8; ++jj) w[jj] = (bf16_t)src[jj * 512];
        ((bf16x8*)W1p)[(f << 6) + lane] = w;
    } else {
        __shared__ float h[ND];
        __shared__ float part[256];
        int bi = blockIdx.x - 128;                    // 0..127
        int b = bi >> 2, ug = bi & 3;
        int t = threadIdx.x;
        h[t] = hidden[b * ND + t];
        h[t + 256] = hidden[b * ND + t + 256];
        __syncthreads();
        int u = (ug << 7) + (t & 127);
        int d0 = (t >> 7) << 8;                       // 0 or 256
        float acc = 0.f;
#pragma unroll 8
        for (int d = d0; d < d0 + 256; ++d) acc = fmaf(h[d], W2[d * NU + u], acc);
        part[t] = acc;
        __syncthreads();
        if (t < 128) hproj[b * NU + u] = part[t] + part[t + 128];
    }
}

// ---------------------------------------------------------------------------
// K2: scores[m] += sum_{n in half} tanh((passage@W1)[m][n] + hproj[b][n]) * Vw[n]
// Round-5 post-mortem: three staging pipelines (ring-2/syncthreads, ring-4/
// counted-vmcnt, ring-4/asm-hidden ds_reads) all land at 80-90us with every
// pipe <25% busy -> the per-kc block-wide barrier + per-kc cvt is the
// structural cost, not waitcnt placement. Round-6: stage the ENTIRE 64x512
// A-tile ONCE as bf16 into a 64KB XOR-swizzled LDS tile (ds_write side, so
// swizzle is legal - global_load_lds couldn't), ONE barrier, then the whole
// 16-kc MFMA loop runs barrier-free: per kc per wave = 4 ds_read_b128 (bf16
// A-frags, <=2-way conflicts) + 4 bb L2 loads (reg double-buffer) + 16 MFMA.
// No DMA, no asm, no per-kc cvt (conversion done once at staging).
// Swizzle: logical kbyte kb of row r stored at kb ^ ((r&7)<<4). Write: lane
// writes full row slice (conflict-free). Read: 16-lane group (rows 0..15,
// fixed kb) spreads over 8 distinct 16B slots (2-way = free, m136).
// LDS 65.5KB + red -> 2 blocks/CU (8 waves). launch_bounds(256,2): 256-reg
// cap, no spill risk (acc 64 AGPR + bb 32 + ~40 addr/staging).
// 4 waves x (64 rows x 64 cols) = 64x256 per block, N split across 2 blocks
// (atomicAdd combine, attn pre-zeroed). XCD-pairing swizzle keeps both
// n-halves of a row-group on the same XCD for passage L2 reuse.
__global__ __launch_bounds__(256, 2) void score_kernel(
    const float* __restrict__ passage, const bf16_t* __restrict__ W1p,
    const float* __restrict__ hproj, const float* __restrict__ Vw,
    const float* __restrict__ Vb, float* __restrict__ scores) {
    __shared__ bf16_t As[64 * 512];               // 64KB, swizzled
    __shared__ float red[4 * 64];
    const int tid = threadIdx.x;
    const int wave = tid >> 6, lane = tid & 63;
    const int q = lane >> 4, c = lane & 15;
    const int bid = blockIdx.x;
    // bids xg*16+{sub, 8+sub} share a row-group and differ by 8 -> same XCD.
    const int mblk = ((bid >> 4) << 3) + (bid & 7); // 0..1023
    const int nhalf = (bid >> 3) & 1;               // n offset 0 / 256
    const int m0 = mblk * 64;
    const int b = m0 >> 11;
    const int ng0 = (nhalf << 4) + (wave << 2);     // 4 n-tiles per wave
    const bf16x8* Wq = (const bf16x8*)W1p;

    // ---- Staging: 16 chunks/thread. Chunk cc: row = cc*4 + wave, this
    // wave's 64 lanes cover the full 512-float row (lane 8 floats = 32B,
    // 2KB contiguous burst per chunk). Convert to bf16, ds_write_b128 at
    // swizzled kbyte = (lane*16) ^ ((row&7)<<4).
#pragma unroll 4
    for (int cc = 0; cc < 16; ++cc) {
        int row = (cc << 2) + wave;
        const float* g = passage + ((size_t)(m0 + row) << 9) + (lane << 3);
        floatx4 f0 = *(const floatx4*)g;
        floatx4 f1 = *(const floatx4*)(g + 4);
        bf16x8 v;
        v[0] = (bf16_t)f0[0]; v[1] = (bf16_t)f0[1];
        v[2] = (bf16_t)f0[2]; v[3] = (bf16_t)f0[3];
        v[4] = (bf16_t)f1[0]; v[5] = (bf16_t)f1[1];
        v[6] = (bf16_t)f1[2]; v[7] = (bf16_t)f1[3];
        unsigned kb = (unsigned)(lane << 4) ^ (unsigned)((row & 7) << 4);
        *(bf16x8*)((char*)As + row * 1024 + kb) = v;
    }

    // B-frags for kc=0 (in flight across the barrier; compiler handles wait).
    bf16x8 bb[2][4];
#pragma unroll
    for (int j = 0; j < 4; ++j)
        bb[0][j] = Wq[((ng0 + j) << 6) + lane];

    __syncthreads();   // the ONLY barrier before the k-loop

    floatx4 acc[4][4];
#pragma unroll
    for (int i = 0; i < 4; ++i)
#pragma unroll
        for (int j = 0; j < 4; ++j) { floatx4 z = {0.f, 0.f, 0.f, 0.f}; acc[i][j] = z; }

#pragma unroll
    for (int kc = 0; kc < 16; ++kc) {
        // Prefetch next B-frags (L2-resident W1p, ~1 iter of slack).
        if (kc < 15) {
#pragma unroll
            for (int j = 0; j < 4; ++j)
                bb[(kc + 1) & 1][j] = Wq[((((kc + 1) << 5) + ng0 + j) << 6) + lane];
        }
#pragma unroll
        for (int i = 0; i < 4; ++i) {
            int row = (i << 4) + c;
            unsigned kb = (unsigned)((kc << 6) + (q << 4)) ^ (unsigned)((row & 7) << 4);
            bf16x8 a = *(const bf16x8*)((const char*)As + row * 1024 + kb);
#pragma unroll
            for (int j = 0; j < 4; ++j)
                acc[i][j] = __builtin_amdgcn_mfma_f32_16x16x32_bf16(a, bb[kc & 1][j], acc[i][j], 0, 0, 0);
        }
    }

    // Epilogue: tanh(x) = 1 - 2/(1+e^{2x}); C/D layout col=c, row=i*16+q*4+r.
    float sp[4][4];
#pragma unroll
    for (int i = 0; i < 4; ++i)
#pragma unroll
        for (int r = 0; r < 4; ++r) sp[i][r] = 0.f;
#pragma unroll
    for (int j = 0; j < 4; ++j) {
        int n = ((ng0 + j) << 4) + c;
        float hp = hproj[(b << 9) + n];
        float vw = Vw[n];
#pragma unroll
        for (int i = 0; i < 4; ++i)
#pragma unroll
            for (int r = 0; r < 4; ++r) {
                float x = acc[i][j][r] + hp;
                float e = __expf(2.0f * x);
                float t = 1.0f - 2.0f * __builtin_amdgcn_rcpf(e + 1.0f);
                sp[i][r] = fmaf(t, vw, sp[i][r]);
            }
    }
#pragma unroll
    for (int off = 1; off < 16; off <<= 1)
#pragma unroll
        for (int i = 0; i < 4; ++i)
#pragma unroll
            for (int r = 0; r < 4; ++r)
                sp[i][r] += __shfl_xor(sp[i][r], off, 64);

    if (c == 0) {
#pragma unroll
        for (int i = 0; i < 4; ++i)
#pragma unroll
            for (int r = 0; r < 4; ++r)
                red[(wave << 6) + (i << 4) + (q << 2) + r] = sp[i][r];
    }
    __syncthreads();
    if (tid < 64) {
        float s = red[tid] + red[64 + tid] + red[128 + tid] + red[192 + tid];
        if (nhalf == 0) s += Vb[0];
        atomicAdd(&scores[m0 + tid], s);
    }
}

// ---------------------------------------------------------------------------
// K3: masked softmax over S, in place on attn. 32 blocks x 1024 threads.
__global__ __launch_bounds__(1024) void softmax_kernel(
    const float* __restrict__ mask, float* __restrict__ attn) {
    __shared__ float smx[16], ssm[16];
    int b = blockIdx.x, tid = threadIdx.x;
    int wave = tid >> 6, lane = tid & 63;
    const int base = b * NS;
    float v0 = attn[base + tid] + (1.0f - mask[base + tid]) * (-1e30f);
    float v1 = attn[base + 1024 + tid] + (1.0f - mask[base + 1024 + tid]) * (-1e30f);
    float mx = fmaxf(v0, v1);
#pragma unroll
    for (int off = 1; off < 64; off <<= 1) mx = fmaxf(mx, __shfl_xor(mx, off, 64));
    if (lane == 0) smx[wave] = mx;
    __syncthreads();
    mx = smx[0];
#pragma unroll
    for (int w = 1; w < 16; ++w) mx = fmaxf(mx, smx[w]);
    v0 = __expf(v0 - mx); v1 = __expf(v1 - mx);
    float sum = v0 + v1;
#pragma unroll
    for (int off = 1; off < 64; off <<= 1) sum += __shfl_xor(sum, off, 64);
    if (lane == 0) ssm[wave] = sum;
    __syncthreads();
    sum = 0.f;
#pragma unroll
    for (int w = 0; w < 16; ++w) sum += ssm[w];
    float inv = 1.0f / sum;
    attn[base + tid] = v0 * inv;
    attn[base + 1024 + tid] = v1 * inv;
}

// ---------------------------------------------------------------------------
// K4: context[b][d] = sum_s attn[b][s] * passage[b][s][d]. 1024 blocks x 512
// threads; 4 quarter-groups of 16 s-rows accumulate in regs, LDS-combine,
// one atomic per (block, d4).
__global__ __launch_bounds__(512) void context_kernel(
    const float* __restrict__ passage, const float* __restrict__ attn,
    float* __restrict__ ctx) {
    __shared__ float4 part[512];
    int bb = blockIdx.x >> 5, sc = blockIdx.x & 31, t = threadIdx.x;
    int col = t & 127, qh = t >> 7;
    const float4* p = (const float4*)(passage + (((size_t)bb * NS + sc * 64 + qh * 16) << 9));
    const float* wp = attn + bb * NS + sc * 64 + qh * 16;
    float ax = 0.f, ay = 0.f, az = 0.f, aw = 0.f;
#pragma unroll 16
    for (int s = 0; s < 16; ++s) {
        float w = wp[s];
        float4 v = p[(size_t)s * 128 + col];
        ax = fmaf(w, v.x, ax); ay = fmaf(w, v.y, ay);
        az = fmaf(w, v.z, az); aw = fmaf(w, v.w, aw);
    }
    float4 mine; mine.x = ax; mine.y = ay; mine.z = az; mine.w = aw;
    part[t] = mine;
    __syncthreads();
    if (t < 128) {
        float4 o1 = part[t + 128], o2 = part[t + 256], o3 = part[t + 384];
        float* dst = ctx + bb * ND + t * 4;
        atomicAdd(dst + 0, ax + o1.x + o2.x + o3.x);
        atomicAdd(dst + 1, ay + o1.y + o2.y + o3.y);
        atomicAdd(dst + 2, az + o1.z + o2.z + o3.z);
        atomicAdd(dst + 3, aw + o1.w + o2.w + o3.w);
    }
}

// ---------------------------------------------------------------------------
extern "C" void kernel_launch(void* const* d_in, const int* in_sizes, int n_in,
                              void* d_out, int out_size, void* d_ws, size_t ws_size,
                              hipStream_t stream) {
    const float* passage = (const float*)d_in[0];
    const float* hidden  = (const float*)d_in[1];
    const float* mask    = (const float*)d_in[2];
    const float* W1      = (const float*)d_in[3];
    const float* W2      = (const float*)d_in[4];
    const float* Vw      = (const float*)d_in[5];
    const float* Vb      = (const float*)d_in[6];

    float* ctx  = (float*)d_out;                    // [32*512]
    float* attn = (float*)d_out + NB * ND;          // [32*2048] (score scratch)

    bf16_t* W1p  = (bf16_t*)d_ws;                               // 512KB
    float* hproj = (float*)((char*)d_ws + (size_t)NU * ND * 2); // 64KB

    hipMemsetAsync(ctx, 0, (size_t)NB * (ND + NS) * sizeof(float), stream);
    prep_kernel<<<dim3(256), dim3(256), 0, stream>>>(W1, W1p, hidden, W2, hproj);
    score_kernel<<<dim3(2 * NB * NS / 64), dim3(256), 0, stream>>>(passage, W1p, hproj, Vw, Vb, attn);
    softmax_kernel<<<dim3(NB), dim3(1024), 0, stream>>>(mask, attn);
    context_kernel<<<dim3(NB * 32), dim3(512), 0, stream>>>(passage, attn, ctx);
}

// Round 8
// 272.488 us; speedup vs baseline: 1.0463x; 1.0463x over previous
//
#include <hip/hip_runtime.h>
#include <hip/hip_bf16.h>
#include <cstddef>

// OutputAttention: context = softmax_s(tanh(passage@W1 + hidden@W2)@Vw) . passage
// B=32, S=2048, D=512, U=512. All inputs fp32; outputs fp32.
// d_out = context[32*512] ++ attn[32*2048]. attn region doubles as score scratch.

#define NB 32
#define NS 2048
#define ND 512
#define NU 512

typedef __bf16 bf16_t;
typedef __bf16 bf16x8 __attribute__((ext_vector_type(8)));
typedef float floatx4 __attribute__((ext_vector_type(4)));

// ---------------------------------------------------------------------------
// K0 fused: blocks [0,128): W1 fp32->bf16 swizzle into MFMA-B fragment order,
//           one 1KB frag per wave (gather-read, coalesced 16B writes).
//           blocks [128,256): hproj[b][u] = sum_d hidden[b][d]*W2[d][u].
// B-frag layout: frag f=(kc,ng); lane L holds B[kc*32+q*8+jj][ng*16+c], jj=0..7,
// at W1p[f*512 + L*8] -> k-loop B loads are one coalesced dwordx4 per lane.
__global__ __launch_bounds__(256) void prep_kernel(
    const float* __restrict__ W1, bf16_t* __restrict__ W1p,
    const float* __restrict__ hidden, const float* __restrict__ W2,
    float* __restrict__ hproj) {
    if (blockIdx.x < 128) {
        int wave = threadIdx.x >> 6, lane = threadIdx.x & 63;
        int f = (blockIdx.x << 2) + wave;             // 0..511
        int kc = f >> 5, ng = f & 31;
        int q = lane >> 4, c = lane & 15;
        const float* src = W1 + (kc * 32 + q * 8) * 512 + ng * 16 + c;
        bf16x8 w;
#pragma unroll
        for (int jj = 0; jj < 8; ++jj) w[jj] = (bf16_t)src[jj * 512];
        ((bf16x8*)W1p)[(f << 6) + lane] = w;
    } else {
        __shared__ float h[ND];
        __shared__ float part[256];
        int bi = blockIdx.x - 128;                    // 0..127
        int b = bi >> 2, ug = bi & 3;
        int t = threadIdx.x;
        h[t] = hidden[b * ND + t];
        h[t + 256] = hidden[b * ND + t + 256];
        __syncthreads();
        int u = (ug << 7) + (t & 127);
        int d0 = (t >> 7) << 8;                       // 0 or 256
        float acc = 0.f;
#pragma unroll 8
        for (int d = d0; d < d0 + 256; ++d) acc = fmaf(h[d], W2[d * NU + u], acc);
        part[t] = acc;
        __syncthreads();
        if (t < 128) hproj[b * NU + u] = part[t] + part[t + 128];
    }
}

// ---------------------------------------------------------------------------
// K2: scores[m] += sum_{n in half} tanh((passage@W1)[m][n] + hproj[b][n]) * Vw[n]
// Round-6 post-mortem: big-tile structure right, but full unroll of the
// 16-iter kc loop exploded live ranges -> 39MB scratch spill (arch VGPR
// pinned at the 128 step). Round-7 (this kernel; r7 bench was an infra
// failure, resubmitting): kc loop at `#pragma unroll 2` with an EXPLICIT
// 1-deep double-buffer (a_cur/a_nxt, b_cur/b_nxt -> static renaming, live
// set ~150 regs); occupancy pinned via amdgpu_waves_per_eu(2,2) so the
// allocator budgets the full 256-reg step (LDS caps at 2 blocks/CU anyway);
// T5 setprio around the MFMA cluster (2 blocks/CU sit in different phases
// -> scheduler has roles to arbitrate).
// Structure recap: stage whole 64x512 A-tile ONCE as bf16 into XOR-swizzled
// LDS (write-side swizzle via ds_write, legal unlike global_load_lds), ONE
// barrier, then 16 kc of {4 ds_read_b128 + 4 L2 B-loads + 16 MFMA} with no
// further barriers. Swizzle: kbyte ^= (row&7)<<4 -> reads 2-way (free, m136).
// 4 waves x (64 rows x 64 cols) = 64x256 per block, N split across 2 blocks
// (atomicAdd combine, attn pre-zeroed). XCD-pairing swizzle keeps both
// n-halves of a row-group on the same XCD for passage L2 reuse.
__global__ __launch_bounds__(256)
__attribute__((amdgpu_waves_per_eu(2, 2)))
void score_kernel(
    const float* __restrict__ passage, const bf16_t* __restrict__ W1p,
    const float* __restrict__ hproj, const float* __restrict__ Vw,
    const float* __restrict__ Vb, float* __restrict__ scores) {
    __shared__ bf16_t As[64 * 512];               // 64KB, swizzled
    __shared__ float red[4 * 64];
    const int tid = threadIdx.x;
    const int wave = tid >> 6, lane = tid & 63;
    const int q = lane >> 4, c = lane & 15;
    const int bid = blockIdx.x;
    // bids xg*16+{sub, 8+sub} share a row-group and differ by 8 -> same XCD.
    const int mblk = ((bid >> 4) << 3) + (bid & 7); // 0..1023
    const int nhalf = (bid >> 3) & 1;               // n offset 0 / 256
    const int m0 = mblk * 64;
    const int b = m0 >> 11;
    const int ng0 = (nhalf << 4) + (wave << 2);     // 4 n-tiles per wave
    const bf16x8* Wq = (const bf16x8*)W1p;

    // ---- Staging: 16 chunks/thread. Chunk cc: row = cc*4 + wave, this
    // wave's 64 lanes cover the full 512-float row (lane 8 floats = 32B,
    // 2KB contiguous burst per chunk). Convert to bf16, ds_write_b128 at
    // swizzled kbyte = (lane*16) ^ ((row&7)<<4). Staging regs die at the
    // barrier -> no steady-state pressure.
#pragma unroll 4
    for (int cc = 0; cc < 16; ++cc) {
        int row = (cc << 2) + wave;
        const float* g = passage + ((size_t)(m0 + row) << 9) + (lane << 3);
        floatx4 f0 = *(const floatx4*)g;
        floatx4 f1 = *(const floatx4*)(g + 4);
        bf16x8 v;
        v[0] = (bf16_t)f0[0]; v[1] = (bf16_t)f0[1];
        v[2] = (bf16_t)f0[2]; v[3] = (bf16_t)f0[3];
        v[4] = (bf16_t)f1[0]; v[5] = (bf16_t)f1[1];
        v[6] = (bf16_t)f1[2]; v[7] = (bf16_t)f1[3];
        unsigned kb = (unsigned)(lane << 4) ^ (unsigned)((row & 7) << 4);
        *(bf16x8*)((char*)As + row * 1024 + kb) = v;
    }

    // kc=0 B-frags in flight across the barrier.
    bf16x8 b_cur[4], b_nxt[4];
#pragma unroll
    for (int j = 0; j < 4; ++j)
        b_cur[j] = Wq[((ng0 + j) << 6) + lane];

    __syncthreads();   // the ONLY barrier before the k-loop

    floatx4 acc[4][4];
#pragma unroll
    for (int i = 0; i < 4; ++i)
#pragma unroll
        for (int j = 0; j < 4; ++j) { floatx4 z = {0.f, 0.f, 0.f, 0.f}; acc[i][j] = z; }

    // kc=0 A-frags.
    bf16x8 a_cur[4], a_nxt[4];
#pragma unroll
    for (int i = 0; i < 4; ++i) {
        int row = (i << 4) + c;
        unsigned kb = (unsigned)(q << 4) ^ (unsigned)((row & 7) << 4);
        a_cur[i] = *(const bf16x8*)((const char*)As + row * 1024 + kb);
    }

#pragma unroll 2
    for (int kc = 0; kc < 16; ++kc) {
        // Prefetch kc+1 (B from L2, A from LDS) before the MFMA cluster.
        if (kc < 15) {
#pragma unroll
            for (int j = 0; j < 4; ++j)
                b_nxt[j] = Wq[((((kc + 1) << 5) + ng0 + j) << 6) + lane];
#pragma unroll
            for (int i = 0; i < 4; ++i) {
                int row = (i << 4) + c;
                unsigned kb = (unsigned)(((kc + 1) << 6) + (q << 4)) ^ (unsigned)((row & 7) << 4);
                a_nxt[i] = *(const bf16x8*)((const char*)As + row * 1024 + kb);
            }
        }
        __builtin_amdgcn_s_setprio(1);
#pragma unroll
        for (int i = 0; i < 4; ++i)
#pragma unroll
            for (int j = 0; j < 4; ++j)
                acc[i][j] = __builtin_amdgcn_mfma_f32_16x16x32_bf16(a_cur[i], b_cur[j], acc[i][j], 0, 0, 0);
        __builtin_amdgcn_s_setprio(0);
#pragma unroll
        for (int i = 0; i < 4; ++i) a_cur[i] = a_nxt[i];
#pragma unroll
        for (int j = 0; j < 4; ++j) b_cur[j] = b_nxt[j];
    }

    // Epilogue: tanh(x) = 1 - 2/(1+e^{2x}); C/D layout col=c, row=i*16+q*4+r.
    float sp[4][4];
#pragma unroll
    for (int i = 0; i < 4; ++i)
#pragma unroll
        for (int r = 0; r < 4; ++r) sp[i][r] = 0.f;
#pragma unroll
    for (int j = 0; j < 4; ++j) {
        int n = ((ng0 + j) << 4) + c;
        float hp = hproj[(b << 9) + n];
        float vw = Vw[n];
#pragma unroll
        for (int i = 0; i < 4; ++i)
#pragma unroll
            for (int r = 0; r < 4; ++r) {
                float x = acc[i][j][r] + hp;
                float e = __expf(2.0f * x);
                float t = 1.0f - 2.0f * __builtin_amdgcn_rcpf(e + 1.0f);
                sp[i][r] = fmaf(t, vw, sp[i][r]);
            }
    }
#pragma unroll
    for (int off = 1; off < 16; off <<= 1)
#pragma unroll
        for (int i = 0; i < 4; ++i)
#pragma unroll
            for (int r = 0; r < 4; ++r)
                sp[i][r] += __shfl_xor(sp[i][r], off, 64);

    if (c == 0) {
#pragma unroll
        for (int i = 0; i < 4; ++i)
#pragma unroll
            for (int r = 0; r < 4; ++r)
                red[(wave << 6) + (i << 4) + (q << 2) + r] = sp[i][r];
    }
    __syncthreads();
    if (tid < 64) {
        float s = red[tid] + red[64 + tid] + red[128 + tid] + red[192 + tid];
        if (nhalf == 0) s += Vb[0];
        atomicAdd(&scores[m0 + tid], s);
    }
}

// ---------------------------------------------------------------------------
// K3: masked softmax over S, in place on attn. 32 blocks x 1024 threads.
__global__ __launch_bounds__(1024) void softmax_kernel(
    const float* __restrict__ mask, float* __restrict__ attn) {
    __shared__ float smx[16], ssm[16];
    int b = blockIdx.x, tid = threadIdx.x;
    int wave = tid >> 6, lane = tid & 63;
    const int base = b * NS;
    float v0 = attn[base + tid] + (1.0f - mask[base + tid]) * (-1e30f);
    float v1 = attn[base + 1024 + tid] + (1.0f - mask[base + 1024 + tid]) * (-1e30f);
    float mx = fmaxf(v0, v1);
#pragma unroll
    for (int off = 1; off < 64; off <<= 1) mx = fmaxf(mx, __shfl_xor(mx, off, 64));
    if (lane == 0) smx[wave] = mx;
    __syncthreads();
    mx = smx[0];
#pragma unroll
    for (int w = 1; w < 16; ++w) mx = fmaxf(mx, smx[w]);
    v0 = __expf(v0 - mx); v1 = __expf(v1 - mx);
    float sum = v0 + v1;
#pragma unroll
    for (int off = 1; off < 64; off <<= 1) sum += __shfl_xor(sum, off, 64);
    if (lane == 0) ssm[wave] = sum;
    __syncthreads();
    sum = 0.f;
#pragma unroll
    for (int w = 0; w < 16; ++w) sum += ssm[w];
    float inv = 1.0f / sum;
    attn[base + tid] = v0 * inv;
    attn[base + 1024 + tid] = v1 * inv;
}

// ---------------------------------------------------------------------------
// K4: context[b][d] = sum_s attn[b][s] * passage[b][s][d]. 1024 blocks x 512
// threads; 4 quarter-groups of 16 s-rows accumulate in regs, LDS-combine,
// one atomic per (block, d4).
__global__ __launch_bounds__(512) void context_kernel(
    const float* __restrict__ passage, const float* __restrict__ attn,
    float* __restrict__ ctx) {
    __shared__ float4 part[512];
    int bb = blockIdx.x >> 5, sc = blockIdx.x & 31, t = threadIdx.x;
    int col = t & 127, qh = t >> 7;
    const float4* p = (const float4*)(passage + (((size_t)bb * NS + sc * 64 + qh * 16) << 9));
    const float* wp = attn + bb * NS + sc * 64 + qh * 16;
    float ax = 0.f, ay = 0.f, az = 0.f, aw = 0.f;
#pragma unroll 16
    for (int s = 0; s < 16; ++s) {
        float w = wp[s];
        float4 v = p[(size_t)s * 128 + col];
        ax = fmaf(w, v.x, ax); ay = fmaf(w, v.y, ay);
        az = fmaf(w, v.z, az); aw = fmaf(w, v.w, aw);
    }
    float4 mine; mine.x = ax; mine.y = ay; mine.z = az; mine.w = aw;
    part[t] = mine;
    __syncthreads();
    if (t < 128) {
        float4 o1 = part[t + 128], o2 = part[t + 256], o3 = part[t + 384];
        float* dst = ctx + bb * ND + t * 4;
        atomicAdd(dst + 0, ax + o1.x + o2.x + o3.x);
        atomicAdd(dst + 1, ay + o1.y + o2.y + o3.y);
        atomicAdd(dst + 2, az + o1.z + o2.z + o3.z);
        atomicAdd(dst + 3, aw + o1.w + o2.w + o3.w);
    }
}

// ---------------------------------------------------------------------------
extern "C" void kernel_launch(void* const* d_in, const int* in_sizes, int n_in,
                              void* d_out, int out_size, void* d_ws, size_t ws_size,
                              hipStream_t stream) {
    const float* passage = (const float*)d_in[0];
    const float* hidden  = (const float*)d_in[1];
    const float* mask    = (const float*)d_in[2];
    const float* W1      = (const float*)d_in[3];
    const float* W2      = (const float*)d_in[4];
    const float* Vw      = (const float*)d_in[5];
    const float* Vb      = (const float*)d_in[6];

    float* ctx  = (float*)d_out;                    // [32*512]
    float* attn = (float*)d_out + NB * ND;          // [32*2048] (score scratch)

    bf16_t* W1p  = (bf16_t*)d_ws;                               // 512KB
    float* hproj = (float*)((char*)d_ws + (size_t)NU * ND * 2); // 64KB

    hipMemsetAsync(ctx, 0, (size_t)NB * (ND + NS) * sizeof(float), stream);
    prep_kernel<<<dim3(256), dim3(256), 0, stream>>>(W1, W1p, hidden, W2, hproj);
    score_kernel<<<dim3(2 * NB * NS / 64), dim3(256), 0, stream>>>(passage, W1p, hproj, Vw, Vb, attn);
    softmax_kernel<<<dim3(NB), dim3(1024), 0, stream>>>(mask, attn);
    context_kernel<<<dim3(NB * 32), dim3(512), 0, stream>>>(passage, attn, ctx);
}

// Round 9
// 269.806 us; speedup vs baseline: 1.0567x; 1.0099x over previous
//
#include <hip/hip_runtime.h>
#include <hip/hip_bf16.h>
#include <cstddef>

// OutputAttention: context = softmax_s(tanh(passage@W1 + hidden@W2)@Vw) . passage
// B=32, S=2048, D=512, U=512. All inputs fp32; outputs fp32.
// d_out = context[32*512] ++ attn[32*2048].
// Round-9 pipeline (4 dispatches): memset(ws scores) -> prep -> score ->
// finalize (fused softmax+context, atomic-free). Raw scores live in ws, so
// finalize can overwrite d_out.attn with normalized weights race-free.

#define NB 32
#define NS 2048
#define ND 512
#define NU 512

typedef __bf16 bf16_t;
typedef __bf16 bf16x8 __attribute__((ext_vector_type(8)));
typedef float floatx4 __attribute__((ext_vector_type(4)));

// ---------------------------------------------------------------------------
// K0 fused: blocks [0,128): W1 fp32->bf16 swizzle into MFMA-B fragment order,
//           one 1KB frag per wave (gather-read, coalesced 16B writes).
//           blocks [128,256): hproj[b][u] = sum_d hidden[b][d]*W2[d][u].
// B-frag layout: frag f=(kc,ng); lane L holds B[kc*32+q*8+jj][ng*16+c], jj=0..7,
// at W1p[f*512 + L*8] -> k-loop B loads are one coalesced dwordx4 per lane.
__global__ __launch_bounds__(256) void prep_kernel(
    const float* __restrict__ W1, bf16_t* __restrict__ W1p,
    const float* __restrict__ hidden, const float* __restrict__ W2,
    float* __restrict__ hproj) {
    if (blockIdx.x < 128) {
        int wave = threadIdx.x >> 6, lane = threadIdx.x & 63;
        int f = (blockIdx.x << 2) + wave;             // 0..511
        int kc = f >> 5, ng = f & 31;
        int q = lane >> 4, c = lane & 15;
        const float* src = W1 + (kc * 32 + q * 8) * 512 + ng * 16 + c;
        bf16x8 w;
#pragma unroll
        for (int jj = 0; jj < 8; ++jj) w[jj] = (bf16_t)src[jj * 512];
        ((bf16x8*)W1p)[(f << 6) + lane] = w;
    } else {
        __shared__ float h[ND];
        __shared__ float part[256];
        int bi = blockIdx.x - 128;                    // 0..127
        int b = bi >> 2, ug = bi & 3;
        int t = threadIdx.x;
        h[t] = hidden[b * ND + t];
        h[t + 256] = hidden[b * ND + t + 256];
        __syncthreads();
        int u = (ug << 7) + (t & 127);
        int d0 = (t >> 7) << 8;                       // 0 or 256
        float acc = 0.f;
#pragma unroll 8
        for (int d = d0; d < d0 + 256; ++d) acc = fmaf(h[d], W2[d * NU + u], acc);
        part[t] = acc;
        __syncthreads();
        if (t < 128) hproj[b * NU + u] = part[t] + part[t + 128];
    }
}

// ---------------------------------------------------------------------------
// K2: scores[m] += sum_{n in half} tanh((passage@W1)[m][n] + hproj[b][n]) * Vw[n]
// FROZEN at the round-8 version (82us, no spill, conflicts 2.1M, verified):
// stage whole 64x512 A-tile once as bf16 into XOR-swizzled LDS, one barrier,
// 16 kc of {4 ds_read_b128 + 4 L2 B-loads + 16 MFMA} barrier-free, unroll 2
// with explicit a/b double-buffer, waves_per_eu(2,2), setprio around MFMA.
// Four structurally different score kernels (r0/r3/r5/r8) all land 80-95us
// with every pipe <25% busy -> structural; this round pivots to the ~190us
// non-score budget instead. Only change: scores target is a ws buffer.
__global__ __launch_bounds__(256)
__attribute__((amdgpu_waves_per_eu(2, 2)))
void score_kernel(
    const float* __restrict__ passage, const bf16_t* __restrict__ W1p,
    const float* __restrict__ hproj, const float* __restrict__ Vw,
    const float* __restrict__ Vb, float* __restrict__ scores) {
    __shared__ bf16_t As[64 * 512];               // 64KB, swizzled
    __shared__ float red[4 * 64];
    const int tid = threadIdx.x;
    const int wave = tid >> 6, lane = tid & 63;
    const int q = lane >> 4, c = lane & 15;
    const int bid = blockIdx.x;
    // bids xg*16+{sub, 8+sub} share a row-group and differ by 8 -> same XCD.
    const int mblk = ((bid >> 4) << 3) + (bid & 7); // 0..1023
    const int nhalf = (bid >> 3) & 1;               // n offset 0 / 256
    const int m0 = mblk * 64;
    const int b = m0 >> 11;
    const int ng0 = (nhalf << 4) + (wave << 2);     // 4 n-tiles per wave
    const bf16x8* Wq = (const bf16x8*)W1p;

    // Staging: 16 chunks/thread, 2KB contiguous burst per chunk, fp32->bf16
    // once, ds_write_b128 at swizzled kbyte = (lane*16) ^ ((row&7)<<4).
#pragma unroll 4
    for (int cc = 0; cc < 16; ++cc) {
        int row = (cc << 2) + wave;
        const float* g = passage + ((size_t)(m0 + row) << 9) + (lane << 3);
        floatx4 f0 = *(const floatx4*)g;
        floatx4 f1 = *(const floatx4*)(g + 4);
        bf16x8 v;
        v[0] = (bf16_t)f0[0]; v[1] = (bf16_t)f0[1];
        v[2] = (bf16_t)f0[2]; v[3] = (bf16_t)f0[3];
        v[4] = (bf16_t)f1[0]; v[5] = (bf16_t)f1[1];
        v[6] = (bf16_t)f1[2]; v[7] = (bf16_t)f1[3];
        unsigned kb = (unsigned)(lane << 4) ^ (unsigned)((row & 7) << 4);
        *(bf16x8*)((char*)As + row * 1024 + kb) = v;
    }

    bf16x8 b_cur[4], b_nxt[4];
#pragma unroll
    for (int j = 0; j < 4; ++j)
        b_cur[j] = Wq[((ng0 + j) << 6) + lane];

    __syncthreads();   // the ONLY barrier before the k-loop

    floatx4 acc[4][4];
#pragma unroll
    for (int i = 0; i < 4; ++i)
#pragma unroll
        for (int j = 0; j < 4; ++j) { floatx4 z = {0.f, 0.f, 0.f, 0.f}; acc[i][j] = z; }

    bf16x8 a_cur[4], a_nxt[4];
#pragma unroll
    for (int i = 0; i < 4; ++i) {
        int row = (i << 4) + c;
        unsigned kb = (unsigned)(q << 4) ^ (unsigned)((row & 7) << 4);
        a_cur[i] = *(const bf16x8*)((const char*)As + row * 1024 + kb);
    }

#pragma unroll 2
    for (int kc = 0; kc < 16; ++kc) {
        if (kc < 15) {
#pragma unroll
            for (int j = 0; j < 4; ++j)
                b_nxt[j] = Wq[((((kc + 1) << 5) + ng0 + j) << 6) + lane];
#pragma unroll
            for (int i = 0; i < 4; ++i) {
                int row = (i << 4) + c;
                unsigned kb = (unsigned)(((kc + 1) << 6) + (q << 4)) ^ (unsigned)((row & 7) << 4);
                a_nxt[i] = *(const bf16x8*)((const char*)As + row * 1024 + kb);
            }
        }
        __builtin_amdgcn_s_setprio(1);
#pragma unroll
        for (int i = 0; i < 4; ++i)
#pragma unroll
            for (int j = 0; j < 4; ++j)
                acc[i][j] = __builtin_amdgcn_mfma_f32_16x16x32_bf16(a_cur[i], b_cur[j], acc[i][j], 0, 0, 0);
        __builtin_amdgcn_s_setprio(0);
#pragma unroll
        for (int i = 0; i < 4; ++i) a_cur[i] = a_nxt[i];
#pragma unroll
        for (int j = 0; j < 4; ++j) b_cur[j] = b_nxt[j];
    }

    // Epilogue: tanh(x) = 1 - 2/(1+e^{2x}); C/D layout col=c, row=i*16+q*4+r.
    float sp[4][4];
#pragma unroll
    for (int i = 0; i < 4; ++i)
#pragma unroll
        for (int r = 0; r < 4; ++r) sp[i][r] = 0.f;
#pragma unroll
    for (int j = 0; j < 4; ++j) {
        int n = ((ng0 + j) << 4) + c;
        float hp = hproj[(b << 9) + n];
        float vw = Vw[n];
#pragma unroll
        for (int i = 0; i < 4; ++i)
#pragma unroll
            for (int r = 0; r < 4; ++r) {
                float x = acc[i][j][r] + hp;
                float e = __expf(2.0f * x);
                float t = 1.0f - 2.0f * __builtin_amdgcn_rcpf(e + 1.0f);
                sp[i][r] = fmaf(t, vw, sp[i][r]);
            }
    }
#pragma unroll
    for (int off = 1; off < 16; off <<= 1)
#pragma unroll
        for (int i = 0; i < 4; ++i)
#pragma unroll
            for (int r = 0; r < 4; ++r)
                sp[i][r] += __shfl_xor(sp[i][r], off, 64);

    if (c == 0) {
#pragma unroll
        for (int i = 0; i < 4; ++i)
#pragma unroll
            for (int r = 0; r < 4; ++r)
                red[(wave << 6) + (i << 4) + (q << 2) + r] = sp[i][r];
    }
    __syncthreads();
    if (tid < 64) {
        float s = red[tid] + red[64 + tid] + red[128 + tid] + red[192 + tid];
        if (nhalf == 0) s += Vb[0];
        atomicAdd(&scores[m0 + tid], s);
    }
}

// ---------------------------------------------------------------------------
// K3' finalize: fused masked-softmax + attn write + context, atomic-free.
// Grid 512 = (b, dc): dc in [0,16) covers d-range dc*32..+32. 512 threads.
// Phase A: block-redundant row max over masked scores (8KB row, cheap -
//   removes the 32-block softmax kernel and its full attn pass).
// Phase B: e = exp(v - mx) -> LDS wlds (unnormalized), block sum -> inv.
// Phase C: stream passage[b][:, dc-slice] ONCE (each element read by exactly
//   one block; d-partitioned -> no atomics, no ctx memset).
// Phase D: LDS-reduce 64 s-groups, ctx = acc*inv; dc==0 writes normalized attn.
__global__ __launch_bounds__(512) void finalize_kernel(
    const float* __restrict__ passage, const float* __restrict__ scores,
    const float* __restrict__ mask, float* __restrict__ attn,
    float* __restrict__ ctx) {
    __shared__ float wlds[NS];            // 8KB unnormalized exp
    __shared__ float4 part[512];          // 8KB reduce scratch
    __shared__ float rmx[8], rsm[8];
    const int b  = blockIdx.x >> 4;
    const int dc = blockIdx.x & 15;
    const int t  = threadIdx.x;
    const int lane = t & 63, wv = t >> 6;

    // Phase A: masked row max (4 score elems per thread, coalesced).
    const float* sc = scores + b * NS;
    const float* mk = mask + b * NS;
    float sv[4];
    float mx = -3.0e38f;
#pragma unroll
    for (int i = 0; i < 4; ++i) {
        int s = t + (i << 9);
        float v = sc[s] + (1.0f - mk[s]) * (-1e30f);
        sv[i] = v;
        mx = fmaxf(mx, v);
    }
#pragma unroll
    for (int off = 1; off < 64; off <<= 1) mx = fmaxf(mx, __shfl_xor(mx, off, 64));
    if (lane == 0) rmx[wv] = mx;
    __syncthreads();
    mx = rmx[0];
#pragma unroll
    for (int w = 1; w < 8; ++w) mx = fmaxf(mx, rmx[w]);

    // Phase B: exp + sum.
    float sum = 0.f;
#pragma unroll
    for (int i = 0; i < 4; ++i) {
        float e = __expf(sv[i] - mx);
        wlds[t + (i << 9)] = e;
        sum += e;
    }
#pragma unroll
    for (int off = 1; off < 64; off <<= 1) sum += __shfl_xor(sum, off, 64);
    if (lane == 0) rsm[wv] = sum;
    __syncthreads();                       // covers wlds + rsm visibility
    sum = 0.f;
#pragma unroll
    for (int w = 0; w < 8; ++w) sum += rsm[w];
    const float inv = 1.0f / sum;

    // Phase C: stream this block's passage slice. Thread (sg, dq):
    // dq = t&7 (float4 within the 32-d chunk), sg = t>>3 in [0,64);
    // s = sg + 64*ss. Per wave-instr: 8x128B segments, fully in flight.
    const int dq = t & 7;
    const int sg = t >> 3;
    const float4* p = (const float4*)(passage + (size_t)b * NS * ND) + dc * 8 + dq;
    float4 acc; acc.x = acc.y = acc.z = acc.w = 0.f;
#pragma unroll 8
    for (int ss = 0; ss < 32; ++ss) {
        int s = sg + (ss << 6);
        float w = wlds[s];
        float4 v = p[(size_t)s * 128];
        acc.x = fmaf(w, v.x, acc.x); acc.y = fmaf(w, v.y, acc.y);
        acc.z = fmaf(w, v.z, acc.z); acc.w = fmaf(w, v.w, acc.w);
    }
    part[t] = acc;
    __syncthreads();

    // Phase D: 8 threads serial-sum 64 s-groups each (conflict-free b128
    // reads), scale by inv, direct ctx store (no atomics).
    if (t < 8) {
        float4 a = part[t];
#pragma unroll 16
        for (int g = 1; g < 64; ++g) {
            float4 o = part[(g << 3) + t];
            a.x += o.x; a.y += o.y; a.z += o.z; a.w += o.w;
        }
        float* dst = ctx + b * ND + dc * 32 + t * 4;
        dst[0] = a.x * inv; dst[1] = a.y * inv;
        dst[2] = a.z * inv; dst[3] = a.w * inv;
    }
    if (dc == 0) {
#pragma unroll
        for (int i = 0; i < 4; ++i) {
            int s = t + (i << 9);
            attn[b * NS + s] = wlds[s] * inv;
        }
    }
}

// ---------------------------------------------------------------------------
extern "C" void kernel_launch(void* const* d_in, const int* in_sizes, int n_in,
                              void* d_out, int out_size, void* d_ws, size_t ws_size,
                              hipStream_t stream) {
    const float* passage = (const float*)d_in[0];
    const float* hidden  = (const float*)d_in[1];
    const float* mask    = (const float*)d_in[2];
    const float* W1      = (const float*)d_in[3];
    const float* W2      = (const float*)d_in[4];
    const float* Vw      = (const float*)d_in[5];
    const float* Vb      = (const float*)d_in[6];

    float* ctx  = (float*)d_out;                    // [32*512]
    float* attn = (float*)d_out + NB * ND;          // [32*2048] normalized weights

    bf16_t* W1p   = (bf16_t*)d_ws;                               // 512KB
    float* hproj  = (float*)((char*)d_ws + (size_t)NU * ND * 2); // 64KB
    float* scores = (float*)((char*)d_ws + (size_t)NU * ND * 2 + (size_t)NB * NU * 4); // 256KB

    hipMemsetAsync(scores, 0, (size_t)NB * NS * sizeof(float), stream);
    prep_kernel<<<dim3(256), dim3(256), 0, stream>>>(W1, W1p, hidden, W2, hproj);
    score_kernel<<<dim3(2 * NB * NS / 64), dim3(256), 0, stream>>>(passage, W1p, hproj, Vw, Vb, scores);
    finalize_kernel<<<dim3(NB * 16), dim3(512), 0, stream>>>(passage, scores, mask, attn, ctx);
}